// Round 1
// baseline (5225.908 us; speedup 1.0000x reference)
//
#include <hip/hip_runtime.h>
#include <math.h>

#define DEVFN __device__ __forceinline__

namespace {

constexpr int NW = 320, NH = 320, NHW = NW * NH, NB = 4;
constexpr int NC2 = 2 * NHW;            // floats per complex image (re plane + im plane)
constexpr float RHOc = 1.0f;
constexpr float THRESHc = 0.01f;        // LAMBDA_TV / RHO
constexpr int S_RSOLD = 0, S_ALPHA = 1, S_BETA = 2, S_CGDONE = 3,
              S_ADONE = 4, S_COUNT = 5, S_PRES = 6, S_DRES = 7;

struct C2 { float x, y; };

DEVFN C2 cmul(C2 a, C2 b) { return C2{a.x * b.x - a.y * b.y, a.x * b.y + a.y * b.x}; }

template <int SIGN>
DEVFN C2 TWf(const float2* tw, int m) {
  float2 t = tw[m];
  return C2{t.x, (SIGN < 0) ? t.y : -t.y};
}

// 320-point FFT (unnormalized). Input: c[j] = x[lane + 64*j]. Output: c[q] = X[5*lane + q].
// 64 lanes per line; L is a 320-entry float2 LDS region for this line. tw = cis(-2*pi*m/320).
template <int SIGN>
__device__ void fft320(C2 c[5], float2* L, int lane, const float2* tw) {
  C2 t[5];
  // radix-5 (n = n1 + 64*n2): t_q[n1] = sum_{n2} x * w5^{n2 q}, then * w320^{n1 q}
#pragma unroll
  for (int q = 0; q < 5; q++) {
    C2 acc = c[0];
#pragma unroll
    for (int j = 1; j < 5; j++) {
      C2 w = TWf<SIGN>(tw, 64 * ((j * q) % 5));
      C2 m = cmul(c[j], w);
      acc.x += m.x; acc.y += m.y;
    }
    t[q] = cmul(acc, TWf<SIGN>(tw, (lane * q) % 320));
  }
#pragma unroll
  for (int q = 0; q < 5; q++) L[q * 64 + lane] = make_float2(t[q].x, t[q].y);
  __syncthreads();
  // 3 Stockham radix-4 stages over the 64-dim (output-centric, natural order out)
#pragma unroll
  for (int st = 0; st < 3; st++) {
    const int Ls = 1 << (2 * st);
    const int Lr = 4 * Ls;
    const int tf = 320 / Lr;  // 80, 20, 5
    int blk = lane / Lr;
    int kk = lane % Ls;
    int rr = lane % Lr;
    int base = blk * Ls + kk;
    C2 nt[5];
#pragma unroll
    for (int q = 0; q < 5; q++) {
      C2 acc{0.f, 0.f};
#pragma unroll
      for (int p = 0; p < 4; p++) {
        float2 v = L[q * 64 + base + 16 * p];
        C2 w = TWf<SIGN>(tw, (p * rr * tf) % 320);
        acc.x += v.x * w.x - v.y * w.y;
        acc.y += v.x * w.y + v.y * w.x;
      }
      nt[q] = acc;
    }
    __syncthreads();
    if (st < 2) {
#pragma unroll
      for (int q = 0; q < 5; q++) L[q * 64 + lane] = make_float2(nt[q].x, nt[q].y);
      __syncthreads();
    }
#pragma unroll
    for (int q = 0; q < 5; q++) c[q] = nt[q];
  }
}

// ---------------- generic 1D FFT pass (4 lines/block, 256 threads) ----------------
// axis 0: along W (stride 1, line = row h). axis 1: along H (stride NW, line = col w).
template <int SIGN, bool MODIN, bool MODOUT, bool RAWMASK>
__global__ __launch_bounds__(256) void kfft(const float* __restrict__ src,
                                            float* __restrict__ dst,
                                            const float* __restrict__ rawmask,
                                            const float2* __restrict__ twg,
                                            int axis, float scale) {
  __shared__ float2 lds[4][320];
  __shared__ float2 stw[320];
  for (int i = threadIdx.x; i < 320; i += 256) stw[i] = twg[i];
  __syncthreads();
  int wid = threadIdx.x >> 6, lane = threadIdx.x & 63;
  int line = blockIdx.x * 4 + wid;
  int b = line / 320, l = line % 320;
  int base, stride;
  if (axis == 0) { base = b * NC2 + l * NW; stride = 1; }
  else           { base = b * NC2 + l;      stride = NW; }
  C2 c[5];
#pragma unroll
  for (int j = 0; j < 5; j++) {
    int idx = lane + 64 * j;
    float re = src[base + idx * stride];
    float im = src[base + NHW + idx * stride];
    if (RAWMASK) {
      int mi = b * NHW + (axis == 0 ? l * NW + idx : idx * NW + l);
      float m = rawmask[mi];
      re *= m; im *= m;
    }
    if (MODIN && (idx & 1)) { re = -re; im = -im; }
    c[j] = C2{re, im};
  }
  fft320<SIGN>(c, &lds[wid][0], lane, stw);
#pragma unroll
  for (int q = 0; q < 5; q++) {
    int k = 5 * lane + q;
    float re = c[q].x * scale, im = c[q].y * scale;
    if (MODOUT && (k & 1)) { re = -re; im = -im; }
    dst[base + k * stride] = re;
    dst[base + NHW + k * stride] = im;
  }
}

// ------- fused column pass: FFT fwd -> multiply m_is (incl 1/102400) -> IFFT, in place -------
__global__ __launch_bounds__(256) void kfft_colFM(float* __restrict__ data,
                                                  const float* __restrict__ mis,
                                                  const float2* __restrict__ twg) {
  __shared__ float2 lds[4][320];
  __shared__ float2 stw[320];
  for (int i = threadIdx.x; i < 320; i += 256) stw[i] = twg[i];
  __syncthreads();
  int wid = threadIdx.x >> 6, lane = threadIdx.x & 63;
  int line = blockIdx.x * 4 + wid;
  int b = line / 320, w = line % 320;
  int base = b * NC2 + w;
  C2 c[5];
#pragma unroll
  for (int j = 0; j < 5; j++) {
    int idx = lane + 64 * j;
    c[j] = C2{data[base + idx * NW], data[base + NHW + idx * NW]};
  }
  fft320<-1>(c, &lds[wid][0], lane, stw);
  // mask-multiply in freq domain, reorder through LDS to natural order
#pragma unroll
  for (int q = 0; q < 5; q++) {
    int k = 5 * lane + q;
    float m = mis[b * NHW + k * NW + w];
    lds[wid][k] = make_float2(c[q].x * m, c[q].y * m);
  }
  __syncthreads();
#pragma unroll
  for (int j = 0; j < 5; j++) {
    float2 v = lds[wid][lane + 64 * j];
    c[j] = C2{v.x, v.y};
  }
  __syncthreads();
  fft320<1>(c, &lds[wid][0], lane, stw);
#pragma unroll
  for (int q = 0; q < 5; q++) {
    int k = 5 * lane + q;
    data[base + k * NW] = c[q].x;
    data[base + NHW + k * NW] = c[q].y;
  }
}

// G(z) = div_x(dx z_re) + div_y(dx z_im)   (reference's channel-0/1 divergence quirk)
DEVFN float Gfunc(const float* __restrict__ z, int b, int h, int w) {
  const float* re = z + b * NC2;
  const float* im = re + NHW;
  int hw = h * NW + w;
  float divx, divy;
  if (w == 0) {
    divx = re[hw + 1] - re[hw];
  } else if (w < NW - 1) {
    float a = re[hw + 1] - re[hw];
    float bb = re[hw] - re[hw - 1];
    divx = a - bb;
  } else {
    divx = -(re[hw] - re[hw - 1]);
  }
  if (h == 0) {
    divy = (w < NW - 1) ? im[hw + 1] - im[hw] : 0.f;
  } else if (h < NH - 1) {
    float a = (w < NW - 1) ? im[hw + 1] - im[hw] : 0.f;
    float bb = (w < NW - 1) ? im[hw - NW + 1] - im[hw - NW] : 0.f;
    divy = a - bb;
  } else {
    divy = -((w < NW - 1) ? im[hw - NW + 1] - im[hw - NW] : 0.f);
  }
  return divx + divy;
}

// rows-inverse FFT + assemble A(z) = Mop - RHO*G(z); SETUP: r=p=b-A(xc), partial sum r^2.
// ITER: store Ap, partial sum p.Ap.
template <bool SETUP>
__global__ __launch_bounds__(256) void kfft_rowI_A(const float* __restrict__ freq,
                                                   const float* __restrict__ zin,
                                                   const float* __restrict__ bvec,
                                                   float* __restrict__ outR,
                                                   float* __restrict__ outP,
                                                   double* __restrict__ part,
                                                   const float2* __restrict__ twg) {
  __shared__ float2 lds[4][320];
  __shared__ float2 stw[320];
  __shared__ double red[256];
  for (int i = threadIdx.x; i < 320; i += 256) stw[i] = twg[i];
  __syncthreads();
  int wid = threadIdx.x >> 6, lane = threadIdx.x & 63;
  int line = blockIdx.x * 4 + wid;
  int b = line / 320, h = line % 320;
  int base = b * NC2 + h * NW;
  C2 c[5];
#pragma unroll
  for (int j = 0; j < 5; j++) {
    int idx = lane + 64 * j;
    c[j] = C2{freq[base + idx], freq[base + NHW + idx]};
  }
  fft320<1>(c, &lds[wid][0], lane, stw);
  double acc = 0.0;
#pragma unroll
  for (int q = 0; q < 5; q++) {
    int k = 5 * lane + q;
    float G = Gfunc(zin, b, h, k);
    float Ar = c[q].x - RHOc * G;
    float Ai = c[q].y - RHOc * G;
    if (SETUP) {
      float rr = bvec[base + k] - Ar;
      float ri = bvec[base + NHW + k] - Ai;
      outR[base + k] = rr; outR[base + NHW + k] = ri;
      outP[base + k] = rr; outP[base + NHW + k] = ri;
      acc += (double)rr * rr + (double)ri * ri;
    } else {
      outR[base + k] = Ar; outR[base + NHW + k] = Ai;
      float pr = zin[base + k], pi = zin[base + NHW + k];
      acc += (double)pr * Ar + (double)pi * Ai;
    }
  }
  red[threadIdx.x] = acc;
  __syncthreads();
  for (int s = 128; s > 0; s >>= 1) {
    if (threadIdx.x < s) red[threadIdx.x] += red[threadIdx.x + s];
    __syncthreads();
  }
  if (threadIdx.x == 0) part[blockIdx.x] = red[0];
}

// ---------------- small kernels ----------------

__global__ void k_init(float2* tw, float* sc) {
  int t = blockIdx.x * blockDim.x + threadIdx.x;
  if (t < 320) {
    double ang = -2.0 * 3.14159265358979323846 * (double)t / 320.0;
    tw[t] = make_float2((float)cos(ang), (float)sin(ang));
  }
  if (t == 320) {
    sc[S_RSOLD] = 0.f; sc[S_ALPHA] = 0.f; sc[S_BETA] = 0.f; sc[S_CGDONE] = 0.f;
    sc[S_ADONE] = 0.f; sc[S_COUNT] = 0.f; sc[S_PRES] = 0.f; sc[S_DRES] = 0.f;
  }
}

__global__ __launch_bounds__(256) void k_mis(const float* __restrict__ mask, float* __restrict__ mis) {
  int i = blockIdx.x * 256 + threadIdx.x;  // exactly NB*NHW
  int b = i / NHW, hw = i % NHW, h = hw / NW, w = hw % NW;
  int hs = (h + 160) % 320, ws = (w + 160) % 320;
  mis[i] = mask[b * NHW + hs * NW + ws] * (1.0f / 102400.0f);
}

__global__ __launch_bounds__(256) void k_init_uv(const float* __restrict__ x,
                                                 float* __restrict__ u, float* __restrict__ v) {
  int i = blockIdx.x * 256 + threadIdx.x;  // exactly NB*NHW sites
  int b = i / NHW, hw = i % NHW, h = hw / NW, w = hw % NW;
  const float* re = x + b * NC2;
  const float* im = re + NHW;
  float g0 = (w < NW - 1) ? re[hw + 1] - re[hw] : 0.f;
  float g1 = (w < NW - 1) ? im[hw + 1] - im[hw] : 0.f;
  float g2 = (h < NH - 1) ? re[hw + NW] - re[hw] : 0.f;
  float g3 = (h < NH - 1) ? im[hw + NW] - im[hw] : 0.f;
  int b4 = b * 4 * NHW;
  u[b4 + hw] = g0;            v[b4 + hw] = 0.f;
  u[b4 + NHW + hw] = g1;      v[b4 + NHW + hw] = 0.f;
  u[b4 + 2 * NHW + hw] = g2;  v[b4 + 2 * NHW + hw] = 0.f;
  u[b4 + 3 * NHW + hw] = g3;  v[b4 + 3 * NHW + hw] = 0.f;
}

// b = b_data + RHO*(div_x((u-v)0) + div_y((u-v)1)), broadcast to both channels; also xc = x
__global__ __launch_bounds__(256) void k_b(const float* __restrict__ u, const float* __restrict__ v,
                                           const float* __restrict__ bdata, float* __restrict__ bout,
                                           const float* __restrict__ x, float* __restrict__ xc) {
  int i = blockIdx.x * 256 + threadIdx.x;  // exactly NB*NHW
  int b = i / NHW, hw = i % NHW, h = hw / NW, w = hw % NW;
  const float* u0 = u + (b * 4 + 0) * NHW; const float* v0 = v + (b * 4 + 0) * NHW;
  const float* u1 = u + (b * 4 + 1) * NHW; const float* v1 = v + (b * 4 + 1) * NHW;
  float divx, divy;
  if (w == 0)            divx = u0[hw] - v0[hw];
  else if (w < NW - 1)   divx = (u0[hw] - v0[hw]) - (u0[hw - 1] - v0[hw - 1]);
  else                   divx = -(u0[hw - 1] - v0[hw - 1]);
  if (h == 0)            divy = u1[hw] - v1[hw];
  else if (h < NH - 1)   divy = (u1[hw] - v1[hw]) - (u1[hw - NW] - v1[hw - NW]);
  else                   divy = -(u1[hw - NW] - v1[hw - NW]);
  float d = RHOc * (divx + divy);
  int b2 = b * NC2;
  bout[b2 + hw] = bdata[b2 + hw] + d;
  bout[b2 + NHW + hw] = bdata[b2 + NHW + hw] + d;
  xc[b2 + hw] = x[b2 + hw];
  xc[b2 + NHW + hw] = x[b2 + NHW + hw];
}

__device__ double blockReduceD(double v, double* s) {
  int t = threadIdx.x;
  s[t] = v;
  __syncthreads();
  for (int k = 128; k > 0; k >>= 1) {
    if (t < k) s[t] += s[t + k];
    __syncthreads();
  }
  return s[0];
}

__global__ __launch_bounds__(256) void kred_setup(const double* __restrict__ part, int n, float* sc) {
  __shared__ double s[256];
  double a = 0;
  for (int i = threadIdx.x; i < n; i += 256) a += part[i];
  a = blockReduceD(a, s);
  if (threadIdx.x == 0) { sc[S_RSOLD] = (float)a; sc[S_CGDONE] = 0.f; }
}

__global__ __launch_bounds__(256) void kred_alpha(const double* __restrict__ part, int n, float* sc) {
  __shared__ double s[256];
  double a = 0;
  for (int i = threadIdx.x; i < n; i += 256) a += part[i];
  a = blockReduceD(a, s);
  if (threadIdx.x == 0) sc[S_ALPHA] = sc[S_RSOLD] / ((float)a + 1e-12f);
}

__global__ __launch_bounds__(256) void kred_beta(const double* __restrict__ part, int n, float* sc) {
  __shared__ double s[256];
  double a = 0;
  for (int i = threadIdx.x; i < n; i += 256) a += part[i];
  a = blockReduceD(a, s);
  if (threadIdx.x == 0) {
    float rsnew = (float)a;
    float rsold = sc[S_RSOLD];
    float done = sc[S_CGDONE];
    float stop = (rsnew < 1e-10f) ? 1.f : 0.f;
    float beta = rsnew / rsold;
    float nd = fmaxf(done, stop);
    if (nd == 0.f) sc[S_RSOLD] = rsnew;
    sc[S_BETA] = beta;
    sc[S_CGDONE] = nd;
  }
}

// x += alpha p, r -= alpha Ap (if !done); partial sum r^2
__global__ __launch_bounds__(256) void k_xr(float* __restrict__ x, float* __restrict__ r,
                                            const float* __restrict__ p, const float* __restrict__ Ap,
                                            const float* __restrict__ sc, double* __restrict__ part) {
  __shared__ double s[256];
  float alpha = sc[S_ALPHA];
  bool act = (sc[S_CGDONE] == 0.f);
  double acc = 0;
  for (int i = blockIdx.x * 256 + threadIdx.x; i < NB * NC2; i += 640 * 256) {
    if (act) {
      x[i] += alpha * p[i];
      r[i] -= alpha * Ap[i];
    }
    float rv = r[i];
    acc += (double)rv * rv;
  }
  acc = blockReduceD(acc, s);
  if (threadIdx.x == 0) part[blockIdx.x] = acc;
}

__global__ __launch_bounds__(256) void k_p(float* __restrict__ p, const float* __restrict__ r,
                                           const float* __restrict__ sc) {
  if (sc[S_CGDONE] != 0.f) return;
  float beta = sc[S_BETA];
  for (int i = blockIdx.x * 256 + threadIdx.x; i < NB * NC2; i += 640 * 256)
    p[i] = r[i] + beta * p[i];
}

// g = gradient(xn); un = soft(g+v); vn = v+g-un; partial sum (g-un)^2
__global__ __launch_bounds__(256) void k_gu(const float* __restrict__ xn, const float* __restrict__ v,
                                            float* __restrict__ un, float* __restrict__ vn,
                                            double* __restrict__ part) {
  __shared__ double s[256];
  double acc = 0;
  for (int i = blockIdx.x * 256 + threadIdx.x; i < NB * NHW; i += 640 * 256) {
    int b = i / NHW, hw = i % NHW, h = hw / NW, w = hw % NW;
    const float* re = xn + b * NC2;
    const float* im = re + NHW;
    float g[4];
    g[0] = (w < NW - 1) ? re[hw + 1] - re[hw] : 0.f;
    g[1] = (w < NW - 1) ? im[hw + 1] - im[hw] : 0.f;
    g[2] = (h < NH - 1) ? re[hw + NW] - re[hw] : 0.f;
    g[3] = (h < NH - 1) ? im[hw + NW] - im[hw] : 0.f;
#pragma unroll
    for (int cch = 0; cch < 4; cch++) {
      int ui = (b * 4 + cch) * NHW + hw;
      float vv = v[ui];
      float sv = g[cch] + vv;
      float a = fabsf(sv) - THRESHc;
      float uo = (a > 0.f) ? copysignf(a, sv) : 0.f;
      un[ui] = uo;
      vn[ui] = vv + g[cch] - uo;
      float dd = g[cch] - uo;
      acc += (double)dd * dd;
    }
  }
  acc = blockReduceD(acc, s);
  if (threadIdx.x == 0) part[blockIdx.x] = acc;
}

// partial sum (RHO*(div_x((un-u)0)+div_y((un-u)1)))^2
__global__ __launch_bounds__(256) void k_dres(const float* __restrict__ un, const float* __restrict__ u,
                                              double* __restrict__ part) {
  __shared__ double s[256];
  double acc = 0;
  for (int i = blockIdx.x * 256 + threadIdx.x; i < NB * NHW; i += 640 * 256) {
    int b = i / NHW, hw = i % NHW, h = hw / NW, w = hw % NW;
    const float* N0 = un + (b * 4 + 0) * NHW; const float* U0 = u + (b * 4 + 0) * NHW;
    const float* N1 = un + (b * 4 + 1) * NHW; const float* U1 = u + (b * 4 + 1) * NHW;
    float divx, divy;
    if (w == 0)          divx = N0[hw] - U0[hw];
    else if (w < NW - 1) divx = (N0[hw] - U0[hw]) - (N0[hw - 1] - U0[hw - 1]);
    else                 divx = -(N0[hw - 1] - U0[hw - 1]);
    if (h == 0)          divy = N1[hw] - U1[hw];
    else if (h < NH - 1) divy = (N1[hw] - U1[hw]) - (N1[hw - NW] - U1[hw - NW]);
    else                 divy = -(N1[hw - NW] - U1[hw - NW]);
    float d = RHOc * (divx + divy);
    acc += (double)d * d;
  }
  acc = blockReduceD(acc, s);
  if (threadIdx.x == 0) part[blockIdx.x] = acc;
}

__global__ __launch_bounds__(256) void k_commit(float* __restrict__ x, float* __restrict__ u,
                                                float* __restrict__ v, const float* __restrict__ xc,
                                                const float* __restrict__ un, const float* __restrict__ vn,
                                                const float* __restrict__ sc) {
  if (sc[S_ADONE] != 0.f) return;
  for (int i = blockIdx.x * 256 + threadIdx.x; i < 4 * NB * NHW; i += 1280 * 256) {
    u[i] = un[i];
    v[i] = vn[i];
  }
  for (int i = blockIdx.x * 256 + threadIdx.x; i < NB * NC2; i += 1280 * 256) {
    x[i] = xc[i];
  }
}

__global__ __launch_bounds__(256) void kred_admm(const double* __restrict__ pa,
                                                 const double* __restrict__ pb, int n, float* sc) {
  __shared__ double sa[256], sb[256];
  double a = 0, b = 0;
  for (int i = threadIdx.x; i < n; i += 256) { a += pa[i]; b += pb[i]; }
  int t = threadIdx.x;
  sa[t] = a; sb[t] = b;
  __syncthreads();
  for (int k = 128; k > 0; k >>= 1) {
    if (t < k) { sa[t] += sa[t + k]; sb[t] += sb[t + k]; }
    __syncthreads();
  }
  if (t == 0) {
    float pres = sqrtf((float)sa[0]);
    float dres = sqrtf((float)sb[0]);
    float done = sc[S_ADONE];
    if (done == 0.f) {
      sc[S_PRES] = pres;
      sc[S_DRES] = dres;
      sc[S_COUNT] += 1.f;
    }
    float stop = (pres < 1e-4f && dres < 1e-4f) ? 1.f : 0.f;
    sc[S_ADONE] = fmaxf(done, stop);
  }
}

__global__ __launch_bounds__(256) void k_out(const float* __restrict__ x, const float* __restrict__ sc,
                                             float* __restrict__ out) {
  int i = blockIdx.x * 256 + threadIdx.x;  // exactly NB*NC2
  out[i] = x[i];
  if (i == 0) {
    out[NB * NC2 + 0] = sc[S_COUNT];
    out[NB * NC2 + 1] = sc[S_PRES];
    out[NB * NC2 + 2] = sc[S_DRES];
  }
}

}  // namespace

extern "C" void kernel_launch(void* const* d_in, const int* in_sizes, int n_in,
                              void* d_out, int out_size, void* d_ws, size_t ws_size,
                              hipStream_t stream) {
  (void)in_sizes; (void)n_in; (void)out_size; (void)ws_size;
  const float* y = (const float*)d_in[0];
  const float* mask = (const float*)d_in[1];
  float* out = (float*)d_out;
  float* wsf = (float*)d_ws;

  float2* tw = (float2*)wsf;                  // 320 float2 = 640 floats
  float* sc = wsf + 640;                      // 16 floats
  double* pA = (double*)(wsf + 656);          // 640 doubles = 1280 floats
  double* pB = (double*)(wsf + 1936);         // 640 doubles = 1280 floats

  size_t off = 4096;
  auto take = [&](size_t n) { float* ptr = wsf + off; off += n; return ptr; };
  float* mis   = take((size_t)NB * NHW);
  float* t1    = take((size_t)NB * NC2);
  float* x     = take((size_t)NB * NC2);
  float* xc    = take((size_t)NB * NC2);
  float* r     = take((size_t)NB * NC2);
  float* p     = take((size_t)NB * NC2);
  float* Ap    = take((size_t)NB * NC2);
  float* bbuf  = take((size_t)NB * NC2);
  float* bdata = take((size_t)NB * NC2);
  float* u     = take((size_t)NB * 4 * NHW);
  float* v     = take((size_t)NB * 4 * NHW);
  float* un    = take((size_t)NB * 4 * NHW);
  float* vn    = take((size_t)NB * 4 * NHW);

  const int GF = (NB * 320) / 4;  // 320 blocks for FFT kernels
  const int GE = (NB * NHW) / 256;  // 1600 blocks for per-site kernels

  k_init<<<2, 256, 0, stream>>>(tw, sc);
  k_mis<<<GE, 256, 0, stream>>>(mask, mis);

  // x0 = ifft2c(y): per-axis S*IFFT*S, total scale 1/320
  kfft<1, true, true, false><<<GF, 256, 0, stream>>>(y, t1, nullptr, tw, 0, 1.f);
  kfft<1, true, true, false><<<GF, 256, 0, stream>>>(t1, x, nullptr, tw, 1, 1.f / 320.f);
  // b_data = ifft2c(mask * y)
  kfft<1, true, true, true><<<GF, 256, 0, stream>>>(y, t1, mask, tw, 0, 1.f);
  kfft<1, true, true, false><<<GF, 256, 0, stream>>>(t1, bdata, nullptr, tw, 1, 1.f / 320.f);
  // u0 = gradient(x0), v0 = 0
  k_init_uv<<<GE, 256, 0, stream>>>(x, u, v);

  for (int it = 0; it < 10; ++it) {
    k_b<<<GE, 256, 0, stream>>>(u, v, bdata, bbuf, x, xc);
    // CG setup: r = p = b - A(xc); rsold = sum r^2
    kfft<-1, false, false, false><<<GF, 256, 0, stream>>>(xc, t1, nullptr, tw, 0, 1.f);
    kfft_colFM<<<GF, 256, 0, stream>>>(t1, mis, tw);
    kfft_rowI_A<true><<<GF, 256, 0, stream>>>(t1, xc, bbuf, r, p, pA, tw);
    kred_setup<<<1, 256, 0, stream>>>(pA, GF, sc);
    for (int k = 0; k < 10; ++k) {
      kfft<-1, false, false, false><<<GF, 256, 0, stream>>>(p, t1, nullptr, tw, 0, 1.f);
      kfft_colFM<<<GF, 256, 0, stream>>>(t1, mis, tw);
      kfft_rowI_A<false><<<GF, 256, 0, stream>>>(t1, p, nullptr, Ap, nullptr, pA, tw);
      kred_alpha<<<1, 256, 0, stream>>>(pA, GF, sc);
      k_xr<<<640, 256, 0, stream>>>(xc, r, p, Ap, sc, pA);
      kred_beta<<<1, 256, 0, stream>>>(pA, 640, sc);
      k_p<<<640, 256, 0, stream>>>(p, r, sc);
    }
    k_gu<<<640, 256, 0, stream>>>(xc, v, un, vn, pA);
    k_dres<<<640, 256, 0, stream>>>(un, u, pB);
    k_commit<<<1280, 256, 0, stream>>>(x, u, v, xc, un, vn, sc);
    kred_admm<<<1, 256, 0, stream>>>(pA, pB, 640, sc);
  }
  k_out<<<(NB * NC2) / 256, 256, 0, stream>>>(x, sc, out);
}